// Round 1
// baseline (569.388 us; speedup 1.0000x reference)
//
#include <hip/hip_runtime.h>

typedef __bf16 bf16;
typedef __bf16 bf16x8 __attribute__((ext_vector_type(8)));
typedef __bf16 bf16x4 __attribute__((ext_vector_type(4)));
typedef float  f32x4  __attribute__((ext_vector_type(4)));
typedef unsigned int   u32;
typedef unsigned short u16;
typedef u16 u16x4 __attribute__((ext_vector_type(4)));

#define H_    12
#define DIM_  768
#define HD_   64
#define NTOK_ 196
#define BT_   128
#define SCALE_ 0.125f

#define GLOAD_LDS16(g, l)                                                      \
  __builtin_amdgcn_global_load_lds(                                            \
      (const __attribute__((address_space(1))) void*)(g),                      \
      (__attribute__((address_space(3))) void*)(l), 16, 0, 0)

// ---------------------------------------------------------------- weight cast
__global__ __launch_bounds__(256) void cast_kernel(const float* __restrict__ src,
                                                   bf16* __restrict__ dst) {
  int idx = blockIdx.x * 256 + threadIdx.x;
  int e0 = idx * 8;
  const float4* s4 = (const float4*)(src + e0);
  float4 a0 = s4[0], a1 = s4[1];
  bf16x8 o;
  o[0]=(bf16)a0.x; o[1]=(bf16)a0.y; o[2]=(bf16)a0.z; o[3]=(bf16)a0.w;
  o[4]=(bf16)a1.x; o[5]=(bf16)a1.y; o[6]=(bf16)a1.z; o[7]=(bf16)a1.w;
  *(bf16x8*)(dst + e0) = o;
}

// -------------------------------------------------- pos-embed add + bf16 cast
// mode 0: t_x (already [25088][768])   mode 1: s_x (skip CLS: row bt*197+1+n)
__global__ __launch_bounds__(256) void prep_kernel(const float* __restrict__ src,
                                                   const float* __restrict__ pos,
                                                   bf16* __restrict__ dst, int mode) {
  int idx = blockIdx.x * 256 + threadIdx.x;
  int e0 = idx * 8;                       // < 19.3M, fits int
  int m = e0 / DIM_;
  int c = e0 - m * DIM_;
  int n = m % NTOK_;
  long srow = (mode == 0) ? (long)m : ((long)(m / NTOK_) * 197 + 1 + n);
  const float4* s4 = (const float4*)(src + srow * DIM_ + c);
  const float4* p4 = (const float4*)(pos + (long)n * DIM_ + c);
  float4 a0 = s4[0], a1 = s4[1];
  float4 b0 = p4[0], b1 = p4[1];
  bf16x8 o;
  o[0]=(bf16)(a0.x+b0.x); o[1]=(bf16)(a0.y+b0.y);
  o[2]=(bf16)(a0.z+b0.z); o[3]=(bf16)(a0.w+b0.w);
  o[4]=(bf16)(a1.x+b1.x); o[5]=(bf16)(a1.y+b1.y);
  o[6]=(bf16)(a1.z+b1.z); o[7]=(bf16)(a1.w+b1.w);
  *(bf16x8*)(dst + (long)m * DIM_ + c) = o;
}

// --------------------------------------------------------------- GEMM (BT B)
// C[M][N] = A[M][768] * Bt[N][768]^T + bias; 128x128 tile, BK=32, dbuf LDS.
// MODE 0: q  -> out0 = q_ws [bt][h][196][64], *SCALE
// MODE 1: kv -> out0 = k_ws [bt][h][224][64], out1 = v_ws [bt][h][224][64]
// MODE 2: proj -> outf = d_out fp32 [M][768]
template<int MODE, int NBX>
__global__ __launch_bounds__(256) void gemm_bt(
    const bf16* __restrict__ A, const bf16* __restrict__ Bt,
    const float* __restrict__ bias,
    bf16* __restrict__ out0, bf16* __restrict__ out1, float* __restrict__ outf) {
  __shared__ __align__(16) bf16 lds[2][2][128 * 32];
  int bm = blockIdx.x / NBX, bn = blockIdx.x % NBX;
  int tid = threadIdx.x;
  int wave = tid >> 6, lane = tid & 63;
  int g = lane >> 4, li = lane & 15;

  const bf16* Abase = A + (long)bm * 128 * 768;
  const bf16* Bbase = Bt + (long)bn * 128 * 768;

  int srow = lane >> 2;                  // row-in-chunk 0..15
  int sslot = lane & 3;

  // stage one 128x32 A-tile + B-tile into lds[buf]; LDS linear, global source
  // pre-swizzled so ds_read applies byte ^= ((r>>1)&3)<<4  (rule #21)
  auto stage = [&](int buf, int kt) {
    long kb = (long)kt * 64;             // byte offset within a 1536B row
    #pragma unroll
    for (int half = 0; half < 2; ++half) {
      int c = wave + half * 4;           // chunk = 16 rows = 1KB
      int r = c * 16 + srow;
      int ss = sslot ^ ((r >> 1) & 3);
      GLOAD_LDS16((const char*)Abase + (long)r * 1536 + kb + ss * 16,
                  ((char*)&lds[buf][0][0]) + c * 1024);
      GLOAD_LDS16((const char*)Bbase + (long)r * 1536 + kb + ss * 16,
                  ((char*)&lds[buf][1][0]) + c * 1024);
    }
  };

  f32x4 acc[4][4] = {};
  int wm = wave >> 1, wn = wave & 1;
  int arow0 = wm * 64 + li, brow0 = wn * 64 + li;

  stage(0, 0);
  __syncthreads();
  int cur = 0;
  for (int kt = 0; kt < 24; ++kt) {
    if (kt < 23) stage(cur ^ 1, kt + 1);
    bf16x8 af[4], bfr[4];
    #pragma unroll
    for (int f = 0; f < 4; ++f) {
      int ra = arow0 + f * 16;
      af[f]  = *(const bf16x8*)&lds[cur][0][ra * 32 + ((g ^ ((ra >> 1) & 3)) << 3)];
      int rb = brow0 + f * 16;
      bfr[f] = *(const bf16x8*)&lds[cur][1][rb * 32 + ((g ^ ((rb >> 1) & 3)) << 3)];
    }
    #pragma unroll
    for (int mf = 0; mf < 4; ++mf)
      #pragma unroll
      for (int nf = 0; nf < 4; ++nf)
        acc[mf][nf] = __builtin_amdgcn_mfma_f32_16x16x32_bf16(af[mf], bfr[nf], acc[mf][nf], 0, 0, 0);
    __syncthreads();
    cur ^= 1;
  }

  // epilogue: C[row=(l>>4)*4+jj (+mf*16)][col=l&15 (+nf*16)]
  int row_base = bm * 128 + wm * 64 + g * 4;
  int col_base = bn * 128 + wn * 64 + li;
  #pragma unroll
  for (int nf = 0; nf < 4; ++nf) {
    int col = col_base + nf * 16;
    float bv = bias[col];
    #pragma unroll
    for (int mf = 0; mf < 4; ++mf) {
      #pragma unroll
      for (int jj = 0; jj < 4; ++jj) {
        int row = row_base + mf * 16 + jj;
        float v = acc[mf][nf][jj] + bv;
        if (MODE == 0) {
          int bt = row / NTOK_, tok = row - bt * NTOK_;
          int hh = col >> 6, dd = col & 63;
          out0[(((long)bt * H_ + hh) * NTOK_ + tok) * HD_ + dd] = (bf16)(v * SCALE_);
        } else if (MODE == 1) {
          int bt = row / NTOK_, tok = row - bt * NTOK_;
          int dd = col & 63;
          if (col < DIM_) {
            int hh = col >> 6;
            out0[(((long)bt * H_ + hh) * 224 + tok) * HD_ + dd] = (bf16)v;
          } else {
            int hh = (col - DIM_) >> 6;
            out1[(((long)bt * H_ + hh) * 224 + tok) * HD_ + dd] = (bf16)v;
          }
        } else {
          outf[(long)row * DIM_ + col] = v;
        }
      }
    }
  }
}

// ------------------------------------------------------------- V -> V^T tile
// per (bt,h): v [224][64] rows 0..195 -> vt [64][196]
__global__ __launch_bounds__(256) void transpose_v(const u16* __restrict__ v,
                                                   u16* __restrict__ vt) {
  __shared__ u16 tile[196 * 65];
  int pair = blockIdx.x;
  const u16* vsrc = v + (long)pair * 224 * 64;
  u16* vdst = vt + (long)pair * 64 * 196;
  int tid = threadIdx.x;
  for (int i = tid; i < 1568; i += 256) {       // 196 rows * 8 vec/row
    int r = i >> 3;
    int c = (i & 7) * 8;
    uint4 val = *(const uint4*)(vsrc + r * 64 + c);
    u16* t = &tile[r * 65 + c];
    t[0]=(u16)val.x; t[1]=(u16)(val.x>>16);
    t[2]=(u16)val.y; t[3]=(u16)(val.y>>16);
    t[4]=(u16)val.z; t[5]=(u16)(val.z>>16);
    t[6]=(u16)val.w; t[7]=(u16)(val.w>>16);
  }
  __syncthreads();
  for (int i = tid; i < 3136; i += 256) {       // 64 d * 49 quads
    int d = i / 49;
    int kk = (i - d * 49) * 4;
    u16x4 o;
    o[0] = tile[(kk+0) * 65 + d];
    o[1] = tile[(kk+1) * 65 + d];
    o[2] = tile[(kk+2) * 65 + d];
    o[3] = tile[(kk+3) * 65 + d];
    *(u16x4*)(vdst + (long)d * 196 + kk) = o;
  }
}

// ----------------------------------------------------------------- attention
// 1 wave / block; block = (pair, 16-row q-tile). Swapped QK^T: S^T = K*Q^T so
// softmax is lane-local + 2 shfl_xor. Keys padded to 224 (masked >=196).
__global__ __launch_bounds__(64) void attn_kernel(
    const bf16* __restrict__ qws, const bf16* __restrict__ kws,
    const bf16* __restrict__ vtws, bf16* __restrict__ ows) {
  __shared__ __align__(16) bf16 plds[16 * 232];  // stride 232: conflict-free
  int bid = blockIdx.x;
  int tile = bid % 13;
  int pair = bid / 13;
  int bt = pair / H_, h = pair - bt * H_;
  int lane = threadIdx.x;
  int g = lane >> 4, li = lane & 15;
  int q0 = tile * 16;

  const bf16* Q  = qws + (long)pair * NTOK_ * HD_;   // [196][64] (pre-scaled)
  const bf16* K  = kws + (long)pair * 224 * HD_;     // [224][64]
  const bf16* VT = vtws + (long)pair * HD_ * NTOK_;  // [64][196]

  bf16x8 qf0 = *(const bf16x8*)(Q + (q0 + li) * 64 + g * 8);
  bf16x8 qf1 = *(const bf16x8*)(Q + (q0 + li) * 64 + 32 + g * 8);

  f32x4 s[14];
  #pragma unroll
  for (int mf = 0; mf < 14; ++mf) s[mf] = (f32x4){0.f, 0.f, 0.f, 0.f};
  #pragma unroll
  for (int mf = 0; mf < 14; ++mf) {
    bf16x8 kf0 = *(const bf16x8*)(K + (mf * 16 + li) * 64 + g * 8);
    s[mf] = __builtin_amdgcn_mfma_f32_16x16x32_bf16(kf0, qf0, s[mf], 0, 0, 0);
    bf16x8 kf1 = *(const bf16x8*)(K + (mf * 16 + li) * 64 + 32 + g * 8);
    s[mf] = __builtin_amdgcn_mfma_f32_16x16x32_bf16(kf1, qf1, s[mf], 0, 0, 0);
  }

  // lane owns q-row q0+li; its kk values are mf*16 + g*4 + jj
  float mx = -3e38f;
  #pragma unroll
  for (int mf = 0; mf < 14; ++mf)
    #pragma unroll
    for (int jj = 0; jj < 4; ++jj) {
      int kk = mf * 16 + g * 4 + jj;
      float val = s[mf][jj];
      if (kk >= NTOK_) val = -3e38f;
      s[mf][jj] = val;
      mx = fmaxf(mx, val);
    }
  mx = fmaxf(mx, __shfl_xor(mx, 16));
  mx = fmaxf(mx, __shfl_xor(mx, 32));
  float sum = 0.f;
  #pragma unroll
  for (int mf = 0; mf < 14; ++mf)
    #pragma unroll
    for (int jj = 0; jj < 4; ++jj) {
      float e = __expf(s[mf][jj] - mx);
      s[mf][jj] = e;
      sum += e;
    }
  sum += __shfl_xor(sum, 16);
  sum += __shfl_xor(sum, 32);
  float inv = 1.f / sum;

  #pragma unroll
  for (int mf = 0; mf < 14; ++mf) {
    bf16x4 pk;
    pk[0] = (bf16)(s[mf][0] * inv); pk[1] = (bf16)(s[mf][1] * inv);
    pk[2] = (bf16)(s[mf][2] * inv); pk[3] = (bf16)(s[mf][3] * inv);
    *(bf16x4*)(plds + li * 232 + mf * 16 + g * 4) = pk;
  }
  __syncthreads();

  f32x4 o[4];
  #pragma unroll
  for (int nf = 0; nf < 4; ++nf) o[nf] = (f32x4){0.f, 0.f, 0.f, 0.f};
  #pragma unroll
  for (int ks = 0; ks < 7; ++ks) {
    bf16x8 pf = *(const bf16x8*)(plds + li * 232 + ks * 32 + g * 8);
    #pragma unroll
    for (int nf = 0; nf < 4; ++nf) {
      const bf16* vr = VT + (long)(nf * 16 + li) * 196 + ks * 32 + g * 8;
      bf16x4 lo = *(const bf16x4*)vr;          // rows are 8B-aligned only
      bf16x4 hi = *(const bf16x4*)(vr + 4);
      bf16x8 vf = {lo[0], lo[1], lo[2], lo[3], hi[0], hi[1], hi[2], hi[3]};
      o[nf] = __builtin_amdgcn_mfma_f32_16x16x32_bf16(pf, vf, o[nf], 0, 0, 0);
    }
  }

  #pragma unroll
  for (int nf = 0; nf < 4; ++nf)
    #pragma unroll
    for (int jj = 0; jj < 4; ++jj) {
      int q = q0 + g * 4 + jj;
      if (q < NTOK_) {
        int d = nf * 16 + li;
        ows[((long)(bt * NTOK_ + q)) * DIM_ + h * HD_ + d] = (bf16)o[nf][jj];
      }
    }
}

// ------------------------------------------------------------------- launch
extern "C" void kernel_launch(void* const* d_in, const int* in_sizes, int n_in,
                              void* d_out, int out_size, void* d_ws, size_t ws_size,
                              hipStream_t stream) {
  const float* s_x  = (const float*)d_in[0];
  const float* t_x  = (const float*)d_in[1];
  const float* cpos = (const float*)d_in[2];
  const float* vpos = (const float*)d_in[3];
  const float* q_w  = (const float*)d_in[4];
  const float* q_b  = (const float*)d_in[5];
  const float* kv_w = (const float*)d_in[6];
  const float* kv_b = (const float*)d_in[7];
  const float* p_w  = (const float*)d_in[8];
  const float* p_b  = (const float*)d_in[9];

  char* ws = (char*)d_ws;
  const long SZ_TS = 38535168L;                 // 25088*768*2
  bf16* t_bf = (bf16*)(ws);                     // t (bf16); later o
  bf16* s_bf = (bf16*)(ws + SZ_TS);             // s (bf16); later V^T
  bf16* wq   = (bf16*)(ws + 2 * SZ_TS);
  bf16* wkv  = (bf16*)(ws + 2 * SZ_TS + 1179648L);
  bf16* wpj  = (bf16*)(ws + 2 * SZ_TS + 3538944L);
  bf16* q_ws = (bf16*)(ws + 2 * SZ_TS + 4718592L);
  bf16* k_ws = (bf16*)(ws + 2 * SZ_TS + 4718592L + SZ_TS);
  bf16* v_ws = (bf16*)(ws + 2 * SZ_TS + 4718592L + SZ_TS + 44040192L);
  // total: 208,404,480 bytes

  cast_kernel<<<288, 256, 0, stream>>>(q_w, wq);
  cast_kernel<<<576, 256, 0, stream>>>(kv_w, wkv);
  cast_kernel<<<288, 256, 0, stream>>>(p_w, wpj);
  prep_kernel<<<9408, 256, 0, stream>>>(t_x, vpos, t_bf, 0);
  prep_kernel<<<9408, 256, 0, stream>>>(s_x, cpos, s_bf, 1);
  gemm_bt<0, 6><<<196 * 6, 256, 0, stream>>>(t_bf, wq, q_b, q_ws, nullptr, nullptr);
  gemm_bt<1, 12><<<196 * 12, 256, 0, stream>>>(s_bf, wkv, kv_b, k_ws, v_ws, nullptr);
  transpose_v<<<1536, 256, 0, stream>>>((const u16*)v_ws, (u16*)s_bf);
  attn_kernel<<<19968, 64, 0, stream>>>(q_ws, k_ws, s_bf, t_bf);
  gemm_bt<2, 6><<<196 * 6, 256, 0, stream>>>(t_bf, wpj, p_b, nullptr, nullptr, (float*)d_out);
}

// Round 2
// 479.356 us; speedup vs baseline: 1.1878x; 1.1878x over previous
//
#include <hip/hip_runtime.h>

typedef __bf16 bf16;
typedef __bf16 bf16x8 __attribute__((ext_vector_type(8)));
typedef __bf16 bf16x4 __attribute__((ext_vector_type(4)));
typedef float  f32x4  __attribute__((ext_vector_type(4)));
typedef float  f32x16 __attribute__((ext_vector_type(16)));
typedef unsigned int u32;

#define H_    12
#define DIM_  768
#define HD_   64
#define NTOK_ 196
#define SCALE_ 0.125f

#define GLOAD_LDS16(g, l)                                                      \
  __builtin_amdgcn_global_load_lds(                                            \
      (const __attribute__((address_space(1))) void*)(g),                      \
      (__attribute__((address_space(3))) void*)(l), 16, 0, 0)

__device__ inline u32 cvt_pk_bf16(float a, float b) {
  u32 r;
  asm volatile("v_cvt_pk_bf16_f32 %0, %1, %2" : "=v"(r) : "v"(a), "v"(b));
  return r;
}

// ---------------------------------------------------------------- weight cast
__global__ __launch_bounds__(256) void cast_kernel(const float* __restrict__ src,
                                                   bf16* __restrict__ dst) {
  int idx = blockIdx.x * 256 + threadIdx.x;
  int e0 = idx * 8;
  const float4* s4 = (const float4*)(src + e0);
  float4 a0 = s4[0], a1 = s4[1];
  bf16x8 o;
  o[0]=(bf16)a0.x; o[1]=(bf16)a0.y; o[2]=(bf16)a0.z; o[3]=(bf16)a0.w;
  o[4]=(bf16)a1.x; o[5]=(bf16)a1.y; o[6]=(bf16)a1.z; o[7]=(bf16)a1.w;
  *(bf16x8*)(dst + e0) = o;
}

// -------------------------------------------------- pos-embed add + bf16 cast
__global__ __launch_bounds__(256) void prep_kernel(const float* __restrict__ src,
                                                   const float* __restrict__ pos,
                                                   bf16* __restrict__ dst, int mode) {
  int idx = blockIdx.x * 256 + threadIdx.x;
  int e0 = idx * 8;
  int m = e0 / DIM_;
  int c = e0 - m * DIM_;
  int n = m % NTOK_;
  long srow = (mode == 0) ? (long)m : ((long)(m / NTOK_) * 197 + 1 + n);
  const float4* s4 = (const float4*)(src + srow * DIM_ + c);
  const float4* p4 = (const float4*)(pos + (long)n * DIM_ + c);
  float4 a0 = s4[0], a1 = s4[1];
  float4 b0 = p4[0], b1 = p4[1];
  bf16x8 o;
  o[0]=(bf16)(a0.x+b0.x); o[1]=(bf16)(a0.y+b0.y);
  o[2]=(bf16)(a0.z+b0.z); o[3]=(bf16)(a0.w+b0.w);
  o[4]=(bf16)(a1.x+b1.x); o[5]=(bf16)(a1.y+b1.y);
  o[6]=(bf16)(a1.z+b1.z); o[7]=(bf16)(a1.w+b1.w);
  *(bf16x8*)(dst + (long)m * DIM_ + c) = o;
}

// --------------------------------------------------------------- GEMM (BT B)
// MODE 0: q  -> q_ws [pair][196][64] (*SCALE)
// MODE 1: kv -> k_ws [pair][224][64] ; v -> vt_ws [pair][64][224] (V^T)
// MODE 2: proj -> d_out fp32
template<int MODE, int NBX>
__global__ __launch_bounds__(256) void gemm_bt(
    const bf16* __restrict__ A, const bf16* __restrict__ Bt,
    const float* __restrict__ bias,
    bf16* __restrict__ out0, bf16* __restrict__ out1, float* __restrict__ outf) {
  __shared__ __align__(16) bf16 lds[2][2][128 * 32];
  int bm = blockIdx.x / NBX, bn = blockIdx.x % NBX;
  int tid = threadIdx.x;
  int wave = tid >> 6, lane = tid & 63;
  int g = lane >> 4, li = lane & 15;

  const bf16* Abase = A + (long)bm * 128 * 768;
  const bf16* Bbase = Bt + (long)bn * 128 * 768;

  int srow = lane >> 2;
  int sslot = lane & 3;

  auto stage = [&](int buf, int kt) {
    long kb = (long)kt * 64;
    #pragma unroll
    for (int half = 0; half < 2; ++half) {
      int c = wave + half * 4;
      int r = c * 16 + srow;
      int ss = sslot ^ ((r >> 1) & 3);
      GLOAD_LDS16((const char*)Abase + (long)r * 1536 + kb + ss * 16,
                  ((char*)&lds[buf][0][0]) + c * 1024);
      GLOAD_LDS16((const char*)Bbase + (long)r * 1536 + kb + ss * 16,
                  ((char*)&lds[buf][1][0]) + c * 1024);
    }
  };

  f32x4 acc[4][4] = {};
  int wm = wave >> 1, wn = wave & 1;
  int arow0 = wm * 64 + li, brow0 = wn * 64 + li;

  stage(0, 0);
  __syncthreads();
  int cur = 0;
  for (int kt = 0; kt < 24; ++kt) {
    if (kt < 23) stage(cur ^ 1, kt + 1);
    bf16x8 af[4], bfr[4];
    #pragma unroll
    for (int f = 0; f < 4; ++f) {
      int ra = arow0 + f * 16;
      af[f]  = *(const bf16x8*)&lds[cur][0][ra * 32 + ((g ^ ((ra >> 1) & 3)) << 3)];
      int rb = brow0 + f * 16;
      bfr[f] = *(const bf16x8*)&lds[cur][1][rb * 32 + ((g ^ ((rb >> 1) & 3)) << 3)];
    }
    #pragma unroll
    for (int mf = 0; mf < 4; ++mf)
      #pragma unroll
      for (int nf = 0; nf < 4; ++nf)
        acc[mf][nf] = __builtin_amdgcn_mfma_f32_16x16x32_bf16(af[mf], bfr[nf], acc[mf][nf], 0, 0, 0);
    __syncthreads();
    cur ^= 1;
  }

  int row_base = bm * 128 + wm * 64 + g * 4;
  int col_base = bn * 128 + wn * 64 + li;
  #pragma unroll
  for (int nf = 0; nf < 4; ++nf) {
    int col = col_base + nf * 16;
    float bv = bias[col];
    #pragma unroll
    for (int mf = 0; mf < 4; ++mf) {
      int row0 = row_base + mf * 16;          // multiple of 4; 196 % 4 == 0 so
      int bt = row0 / NTOK_;                  // a jj-quad never crosses a bt
      int tok0 = row0 - bt * NTOK_;
      if (MODE == 0) {
        int hh = col >> 6, dd = col & 63;
        #pragma unroll
        for (int jj = 0; jj < 4; ++jj)
          out0[(((long)bt * H_ + hh) * NTOK_ + tok0 + jj) * HD_ + dd] =
              (bf16)((acc[mf][nf][jj] + bv) * SCALE_);
      } else if (MODE == 1) {
        if (col < DIM_) {
          int hh = col >> 6, dd = col & 63;
          #pragma unroll
          for (int jj = 0; jj < 4; ++jj)
            out0[(((long)bt * H_ + hh) * 224 + tok0 + jj) * HD_ + dd] =
                (bf16)(acc[mf][nf][jj] + bv);
        } else {
          int hh = (col - DIM_) >> 6, dd = col & 63;
          bf16x4 pk;
          #pragma unroll
          for (int jj = 0; jj < 4; ++jj) pk[jj] = (bf16)(acc[mf][nf][jj] + bv);
          *(bf16x4*)(out1 + (((long)bt * H_ + hh) * HD_ + dd) * 224 + tok0) = pk;
        }
      } else {
        #pragma unroll
        for (int jj = 0; jj < 4; ++jj)
          outf[(long)(row0 + jj) * DIM_ + col] = acc[mf][nf][jj] + bv;
      }
    }
  }
}

// ----------------------------------------------------------------- attention
// 1 block = 1 (bt,h) pair; 7 waves, wave w owns q-rows [w*32, w*32+32).
// 32x32x16 MFMA. Swapped QK^T: S^T[k][q] = mfma(K_frag, Q_frag) -> lane
// (hi,l5) holds S[kk=kb*32+(reg&3)+8*(reg>>2)+4*hi][q=l5]. Softmax fully in
// register (1 shfl_xor(32) for max and sum). P redistribution for the PV
// A-operand needs only lane<->lane+32 word exchange (shfl_xor 32).
// K/VT staged in LDS, XOR-swizzled slot ^= (row&7) via pre-swizzled global src.
__global__ __launch_bounds__(448) void attn_kernel(
    const bf16* __restrict__ qws, const bf16* __restrict__ kws,
    const bf16* __restrict__ vtws, bf16* __restrict__ ows) {
  __shared__ __align__(16) bf16 k_lds[224 * 64];    // rows 128B = 8 slots
  __shared__ __align__(16) bf16 vt_lds[64 * 256];   // rows 512B = 32 slots
  int pair = blockIdx.x;
  int bt = pair / H_, h = pair - bt * H_;
  int tid = threadIdx.x;
  int wave = tid >> 6, lane = tid & 63;
  int hi = lane >> 5, l5 = lane & 31;

  const char* Kg = (const char*)(kws + (long)pair * 224 * 64);   // stride 128B
  const char* Vg = (const char*)(vtws + (long)pair * 64 * 224);  // stride 448B

  // stage: chunks 0..27 = K, 28..59 = VT (1 KB per chunk = 64 lanes x 16B)
  for (int ch = wave; ch < 60; ch += 7) {
    if (ch < 28) {
      int i = ch * 64 + lane;
      int r = i >> 3, p = i & 7;
      GLOAD_LDS16(Kg + (long)r * 128 + ((p ^ (r & 7)) * 16),
                  (char*)k_lds + ch * 1024);
    } else {
      int i = (ch - 28) * 64 + lane;
      int r = i >> 5, p = i & 31;
      int gs = p ^ (r & 7);
      if (gs > 27) gs = 27;   // junk slot, never read; keep in-bounds
      GLOAD_LDS16(Vg + (long)r * 448 + gs * 16,
                  (char*)vt_lds + (ch - 28) * 1024);
    }
  }

  // Q fragments from global (L2): B-frag col=q=l5, k(hd)=c*16+hi*8+j
  int qr = wave * 32 + l5;
  if (qr > 195) qr = 195;                     // clamp; results masked at store
  const bf16* Qp = qws + (long)pair * NTOK_ * HD_ + qr * 64 + hi * 8;
  bf16x8 qf[4];
  #pragma unroll
  for (int c = 0; c < 4; ++c) qf[c] = *(const bf16x8*)(Qp + c * 16);

  __syncthreads();

  // QK^T: s[kb] = K-block(kb) x Q-tile
  f32x16 s[7] = {};
  #pragma unroll
  for (int kb = 0; kb < 7; ++kb) {
    #pragma unroll
    for (int c = 0; c < 4; ++c) {
      int row = kb * 32 + l5;
      bf16x8 kf = *(const bf16x8*)((char*)k_lds + row * 128 +
                                   (((c * 2 + hi) ^ (row & 7)) << 4));
      s[kb] = __builtin_amdgcn_mfma_f32_32x32x16_bf16(kf, qf[c], s[kb], 0, 0, 0);
    }
  }

  // softmax over kk (mask kk>=196); lane pair (hi=0,1) covers one q-column
  float mx = -1e30f;
  #pragma unroll
  for (int kb = 0; kb < 7; ++kb)
    #pragma unroll
    for (int reg = 0; reg < 16; ++reg) {
      int kk = kb * 32 + (reg & 3) + 8 * (reg >> 2) + 4 * hi;
      float v = s[kb][reg];
      if (kk >= NTOK_) v = -1e30f;
      s[kb][reg] = v;
      mx = fmaxf(mx, v);
    }
  mx = fmaxf(mx, __shfl_xor(mx, 32));
  float sum = 0.f;
  #pragma unroll
  for (int kb = 0; kb < 7; ++kb)
    #pragma unroll
    for (int reg = 0; reg < 16; ++reg) {
      float e = __expf(s[kb][reg] - mx);
      s[kb][reg] = e;
      sum += e;
    }
  sum += __shfl_xor(sum, 32);
  float inv = 1.f / sum;

  // PV: O[q][d] = mfma(A=P_frag, B=VT_frag)
  f32x16 o[2] = {};
  #pragma unroll
  for (int kb = 0; kb < 7; ++kb) {
    u32 w[8];
    #pragma unroll
    for (int m = 0; m < 8; ++m)
      w[m] = cvt_pk_bf16(s[kb][2 * m] * inv, s[kb][2 * m + 1] * inv);
    u32 t0 = __shfl_xor(w[0], 32), t1 = __shfl_xor(w[1], 32);
    u32 t2 = __shfl_xor(w[2], 32), t3 = __shfl_xor(w[3], 32);
    u32 u0 = __shfl_xor(w[4], 32), u1 = __shfl_xor(w[5], 32);
    u32 u2 = __shfl_xor(w[6], 32), u3 = __shfl_xor(w[7], 32);
    int4 fe = make_int4((int)(hi ? t2 : w[0]), (int)(hi ? t3 : w[1]),
                        (int)(hi ? w[2] : t0), (int)(hi ? w[3] : t1));
    int4 fo = make_int4((int)(hi ? u2 : w[4]), (int)(hi ? u3 : w[5]),
                        (int)(hi ? w[6] : u0), (int)(hi ? w[7] : u1));
    bf16x8 pe = *(bf16x8*)&fe;
    bf16x8 po = *(bf16x8*)&fo;
    #pragma unroll
    for (int dv = 0; dv < 2; ++dv) {
      int row = dv * 32 + l5;
      bf16x8 ve = *(const bf16x8*)((char*)vt_lds + row * 512 +
                                   ((((4 * kb + 0) + hi) ^ (row & 7)) << 4));
      o[dv] = __builtin_amdgcn_mfma_f32_32x32x16_bf16(pe, ve, o[dv], 0, 0, 0);
      bf16x8 vo = *(const bf16x8*)((char*)vt_lds + row * 512 +
                                   ((((4 * kb + 2) + hi) ^ (row & 7)) << 4));
      o[dv] = __builtin_amdgcn_mfma_f32_32x32x16_bf16(po, vo, o[dv], 0, 0, 0);
    }
  }

  // store: lane (hi,l5) holds O[q=wave*32+(reg&3)+8*(reg>>2)+4*hi][d=dv*32+l5]
  int q_base = wave * 32;
  #pragma unroll
  for (int dv = 0; dv < 2; ++dv)
    #pragma unroll
    for (int reg = 0; reg < 16; ++reg) {
      int q = q_base + (reg & 3) + 8 * (reg >> 2) + 4 * hi;
      if (q < NTOK_)
        ows[((long)(bt * NTOK_ + q)) * DIM_ + h * HD_ + dv * 32 + l5] =
            (bf16)o[dv][reg];
    }
}

// ------------------------------------------------------------------- launch
extern "C" void kernel_launch(void* const* d_in, const int* in_sizes, int n_in,
                              void* d_out, int out_size, void* d_ws, size_t ws_size,
                              hipStream_t stream) {
  const float* s_x  = (const float*)d_in[0];
  const float* t_x  = (const float*)d_in[1];
  const float* cpos = (const float*)d_in[2];
  const float* vpos = (const float*)d_in[3];
  const float* q_w  = (const float*)d_in[4];
  const float* q_b  = (const float*)d_in[5];
  const float* kv_w = (const float*)d_in[6];
  const float* kv_b = (const float*)d_in[7];
  const float* p_w  = (const float*)d_in[8];
  const float* p_b  = (const float*)d_in[9];

  char* ws = (char*)d_ws;
  const long SZ_TS = 38535168L;                 // 25088*768*2
  bf16* t_bf  = (bf16*)(ws);                    // t (bf16); later o
  bf16* s_bf  = (bf16*)(ws + SZ_TS);            // s (bf16)
  bf16* wq    = (bf16*)(ws + 2 * SZ_TS);
  bf16* wkv   = (bf16*)(ws + 2 * SZ_TS + 1179648L);
  bf16* wpj   = (bf16*)(ws + 2 * SZ_TS + 3538944L);
  bf16* q_ws  = (bf16*)(ws + 2 * SZ_TS + 4718592L);                  // 38.5MB
  bf16* k_ws  = (bf16*)(ws + 2 * SZ_TS + 4718592L + SZ_TS);          // 44MB
  bf16* vt_ws = (bf16*)(ws + 2 * SZ_TS + 4718592L + SZ_TS + 44040192L); // 44MB
  // total: 208,404,480 bytes (same as round 0)

  cast_kernel<<<288, 256, 0, stream>>>(q_w, wq);
  cast_kernel<<<576, 256, 0, stream>>>(kv_w, wkv);
  cast_kernel<<<288, 256, 0, stream>>>(p_w, wpj);
  prep_kernel<<<9408, 256, 0, stream>>>(t_x, vpos, t_bf, 0);
  prep_kernel<<<9408, 256, 0, stream>>>(s_x, cpos, s_bf, 1);
  gemm_bt<0, 6><<<196 * 6, 256, 0, stream>>>(t_bf, wq, q_b, q_ws, nullptr, nullptr);
  gemm_bt<1, 12><<<196 * 12, 256, 0, stream>>>(s_bf, wkv, kv_b, k_ws, vt_ws, nullptr);
  attn_kernel<<<1536, 448, 0, stream>>>(q_ws, k_ws, vt_ws, t_bf);
  gemm_bt<2, 6><<<196 * 6, 256, 0, stream>>>(t_bf, wpj, p_b, nullptr, nullptr, (float*)d_out);
}

// Round 3
// 454.154 us; speedup vs baseline: 1.2537x; 1.0555x over previous
//
#include <hip/hip_runtime.h>

typedef __bf16 bf16;
typedef __bf16 bf16x8 __attribute__((ext_vector_type(8)));
typedef __bf16 bf16x4 __attribute__((ext_vector_type(4)));
typedef float  f32x4  __attribute__((ext_vector_type(4)));
typedef float  f32x16 __attribute__((ext_vector_type(16)));
typedef unsigned int u32;

#define H_    12
#define DIM_  768
#define HD_   64
#define NTOK_ 196
#define SCALE_ 0.125f

#define GLOAD_LDS16(g, l)                                                      \
  __builtin_amdgcn_global_load_lds(                                            \
      (const __attribute__((address_space(1))) void*)(g),                      \
      (__attribute__((address_space(3))) void*)(l), 16, 0, 0)

__device__ inline u32 cvt_pk_bf16(float a, float b) {
  u32 r;
  asm volatile("v_cvt_pk_bf16_f32 %0, %1, %2" : "=v"(r) : "v"(a), "v"(b));
  return r;
}

// ------------------------------------------------- fused weight casts (3-in-1)
__global__ __launch_bounds__(256) void cast3_kernel(
    const float* __restrict__ q_w, const float* __restrict__ kv_w,
    const float* __restrict__ p_w, bf16* __restrict__ wq,
    bf16* __restrict__ wkv, bf16* __restrict__ wpj) {
  int b = blockIdx.x;
  const float* src; bf16* dst; int base;
  if (b < 288)      { src = q_w;  dst = wq;  base = b; }
  else if (b < 864) { src = kv_w; dst = wkv; base = b - 288; }
  else              { src = p_w;  dst = wpj; base = b - 864; }
  int e0 = (base * 256 + threadIdx.x) * 8;
  const float4* s4 = (const float4*)(src + e0);
  float4 a0 = s4[0], a1 = s4[1];
  bf16x8 o;
  o[0]=(bf16)a0.x; o[1]=(bf16)a0.y; o[2]=(bf16)a0.z; o[3]=(bf16)a0.w;
  o[4]=(bf16)a1.x; o[5]=(bf16)a1.y; o[6]=(bf16)a1.z; o[7]=(bf16)a1.w;
  *(bf16x8*)(dst + e0) = o;
}

// --------------------------------- fused pos-embed add + bf16 cast (both streams)
__global__ __launch_bounds__(256) void prep2_kernel(
    const float* __restrict__ t_x, const float* __restrict__ s_x,
    const float* __restrict__ vpos, const float* __restrict__ cpos,
    bf16* __restrict__ t_bf, bf16* __restrict__ s_bf) {
  int b = blockIdx.x;
  const float* src; const float* pos; bf16* dst; int mode;
  if (b < 9408) { src = t_x; pos = vpos; dst = t_bf; mode = 0; }
  else          { src = s_x; pos = cpos; dst = s_bf; mode = 1; b -= 9408; }
  int idx = b * 256 + threadIdx.x;
  int e0 = idx * 8;
  int m = e0 / DIM_;
  int c = e0 - m * DIM_;
  int n = m % NTOK_;
  long srow = (mode == 0) ? (long)m : ((long)(m / NTOK_) * 197 + 1 + n);
  const float4* s4 = (const float4*)(src + srow * DIM_ + c);
  const float4* p4 = (const float4*)(pos + (long)n * DIM_ + c);
  float4 a0 = s4[0], a1 = s4[1];
  float4 b0 = p4[0], b1 = p4[1];
  bf16x8 o;
  o[0]=(bf16)(a0.x+b0.x); o[1]=(bf16)(a0.y+b0.y);
  o[2]=(bf16)(a0.z+b0.z); o[3]=(bf16)(a0.w+b0.w);
  o[4]=(bf16)(a1.x+b1.x); o[5]=(bf16)(a1.y+b1.y);
  o[6]=(bf16)(a1.z+b1.z); o[7]=(bf16)(a1.w+b1.w);
  *(bf16x8*)(dst + (long)m * DIM_ + c) = o;
}

// --------------------------------------------------------------- GEMM (BT B)
// MODE 0: q  -> q_ws [pair][196][64] (*SCALE)
// MODE 1: kv -> k_ws [pair][224][64] ; v -> vt_ws [pair][64][224] (V^T)
// MODE 2: proj -> d_out fp32
// T1: chunked XCD swizzle (NWG % 8 == 0 for all instantiations) so the NBX
// blocks sharing an A-tile land on ONE XCD's L2 instead of round-robin 8.
template<int MODE, int NBX>
__global__ __launch_bounds__(256) void gemm_bt(
    const bf16* __restrict__ A, const bf16* __restrict__ Bt,
    const float* __restrict__ bias,
    bf16* __restrict__ out0, bf16* __restrict__ out1, float* __restrict__ outf) {
  __shared__ __align__(16) bf16 lds[2][2][128 * 32];
  constexpr int NWG = 196 * NBX;
  constexpr int CPX = NWG / 8;
  int bid = blockIdx.x;
  int wgid = (bid & 7) * CPX + (bid >> 3);
  int bm = wgid / NBX, bn = wgid % NBX;
  int tid = threadIdx.x;
  int wave = tid >> 6, lane = tid & 63;
  int g = lane >> 4, li = lane & 15;

  const bf16* Abase = A + (long)bm * 128 * 768;
  const bf16* Bbase = Bt + (long)bn * 128 * 768;

  int srow = lane >> 2;
  int sslot = lane & 3;

  auto stage = [&](int buf, int kt) {
    long kb = (long)kt * 64;
    #pragma unroll
    for (int half = 0; half < 2; ++half) {
      int c = wave + half * 4;
      int r = c * 16 + srow;
      int ss = sslot ^ ((r >> 1) & 3);
      GLOAD_LDS16((const char*)Abase + (long)r * 1536 + kb + ss * 16,
                  ((char*)&lds[buf][0][0]) + c * 1024);
      GLOAD_LDS16((const char*)Bbase + (long)r * 1536 + kb + ss * 16,
                  ((char*)&lds[buf][1][0]) + c * 1024);
    }
  };

  f32x4 acc[4][4] = {};
  int wm = wave >> 1, wn = wave & 1;
  int arow0 = wm * 64 + li, brow0 = wn * 64 + li;

  stage(0, 0);
  __syncthreads();
  int cur = 0;
  for (int kt = 0; kt < 24; ++kt) {
    if (kt < 23) stage(cur ^ 1, kt + 1);
    bf16x8 af[4], bfr[4];
    #pragma unroll
    for (int f = 0; f < 4; ++f) {
      int ra = arow0 + f * 16;
      af[f]  = *(const bf16x8*)&lds[cur][0][ra * 32 + ((g ^ ((ra >> 1) & 3)) << 3)];
      int rb = brow0 + f * 16;
      bfr[f] = *(const bf16x8*)&lds[cur][1][rb * 32 + ((g ^ ((rb >> 1) & 3)) << 3)];
    }
    #pragma unroll
    for (int mf = 0; mf < 4; ++mf)
      #pragma unroll
      for (int nf = 0; nf < 4; ++nf)
        acc[mf][nf] = __builtin_amdgcn_mfma_f32_16x16x32_bf16(af[mf], bfr[nf], acc[mf][nf], 0, 0, 0);
    __syncthreads();
    cur ^= 1;
  }

  int row_base = bm * 128 + wm * 64 + g * 4;
  int col_base = bn * 128 + wn * 64 + li;
  #pragma unroll
  for (int nf = 0; nf < 4; ++nf) {
    int col = col_base + nf * 16;
    float bv = bias[col];
    #pragma unroll
    for (int mf = 0; mf < 4; ++mf) {
      int row0 = row_base + mf * 16;          // multiple of 4; 196 % 4 == 0 so
      int bt = row0 / NTOK_;                  // a jj-quad never crosses a bt
      int tok0 = row0 - bt * NTOK_;
      if (MODE == 0) {
        int hh = col >> 6, dd = col & 63;
        #pragma unroll
        for (int jj = 0; jj < 4; ++jj)
          out0[(((long)bt * H_ + hh) * NTOK_ + tok0 + jj) * HD_ + dd] =
              (bf16)((acc[mf][nf][jj] + bv) * SCALE_);
      } else if (MODE == 1) {
        if (col < DIM_) {
          int hh = col >> 6, dd = col & 63;
          #pragma unroll
          for (int jj = 0; jj < 4; ++jj)
            out0[(((long)bt * H_ + hh) * 224 + tok0 + jj) * HD_ + dd] =
                (bf16)(acc[mf][nf][jj] + bv);
        } else {
          int hh = (col - DIM_) >> 6, dd = col & 63;
          bf16x4 pk;
          #pragma unroll
          for (int jj = 0; jj < 4; ++jj) pk[jj] = (bf16)(acc[mf][nf][jj] + bv);
          *(bf16x4*)(out1 + (((long)bt * H_ + hh) * HD_ + dd) * 224 + tok0) = pk;
        }
      } else {
        #pragma unroll
        for (int jj = 0; jj < 4; ++jj)
          outf[(long)(row0 + jj) * DIM_ + col] = acc[mf][nf][jj] + bv;
      }
    }
  }
}

// ----------------------------------------------------------------- attention
// 1 block = 1 (bt,h) pair; 7 waves; 32x32x16 MFMA; in-register softmax.
__global__ __launch_bounds__(448) void attn_kernel(
    const bf16* __restrict__ qws, const bf16* __restrict__ kws,
    const bf16* __restrict__ vtws, bf16* __restrict__ ows) {
  __shared__ __align__(16) bf16 k_lds[224 * 64];    // rows 128B = 8 slots
  __shared__ __align__(16) bf16 vt_lds[64 * 256];   // rows 512B = 32 slots
  int pair = blockIdx.x;
  int bt = pair / H_, h = pair - bt * H_;
  int tid = threadIdx.x;
  int wave = tid >> 6, lane = tid & 63;
  int hi = lane >> 5, l5 = lane & 31;

  const char* Kg = (const char*)(kws + (long)pair * 224 * 64);   // stride 128B
  const char* Vg = (const char*)(vtws + (long)pair * 64 * 224);  // stride 448B

  for (int ch = wave; ch < 60; ch += 7) {
    if (ch < 28) {
      int i = ch * 64 + lane;
      int r = i >> 3, p = i & 7;
      GLOAD_LDS16(Kg + (long)r * 128 + ((p ^ (r & 7)) * 16),
                  (char*)k_lds + ch * 1024);
    } else {
      int i = (ch - 28) * 64 + lane;
      int r = i >> 5, p = i & 31;
      int gs = p ^ (r & 7);
      if (gs > 27) gs = 27;   // junk slot, never read; keep in-bounds
      GLOAD_LDS16(Vg + (long)r * 448 + gs * 16,
                  (char*)vt_lds + (ch - 28) * 1024);
    }
  }

  int qr = wave * 32 + l5;
  if (qr > 195) qr = 195;                     // clamp; results masked at store
  const bf16* Qp = qws + (long)pair * NTOK_ * HD_ + qr * 64 + hi * 8;
  bf16x8 qf[4];
  #pragma unroll
  for (int c = 0; c < 4; ++c) qf[c] = *(const bf16x8*)(Qp + c * 16);

  __syncthreads();

  f32x16 s[7] = {};
  #pragma unroll
  for (int kb = 0; kb < 7; ++kb) {
    #pragma unroll
    for (int c = 0; c < 4; ++c) {
      int row = kb * 32 + l5;
      bf16x8 kf = *(const bf16x8*)((char*)k_lds + row * 128 +
                                   (((c * 2 + hi) ^ (row & 7)) << 4));
      s[kb] = __builtin_amdgcn_mfma_f32_32x32x16_bf16(kf, qf[c], s[kb], 0, 0, 0);
    }
  }

  float mx = -1e30f;
  #pragma unroll
  for (int kb = 0; kb < 7; ++kb)
    #pragma unroll
    for (int reg = 0; reg < 16; ++reg) {
      int kk = kb * 32 + (reg & 3) + 8 * (reg >> 2) + 4 * hi;
      float v = s[kb][reg];
      if (kk >= NTOK_) v = -1e30f;
      s[kb][reg] = v;
      mx = fmaxf(mx, v);
    }
  mx = fmaxf(mx, __shfl_xor(mx, 32));
  float sum = 0.f;
  #pragma unroll
  for (int kb = 0; kb < 7; ++kb)
    #pragma unroll
    for (int reg = 0; reg < 16; ++reg) {
      float e = __expf(s[kb][reg] - mx);
      s[kb][reg] = e;
      sum += e;
    }
  sum += __shfl_xor(sum, 32);
  float inv = 1.f / sum;

  f32x16 o[2] = {};
  #pragma unroll
  for (int kb = 0; kb < 7; ++kb) {
    u32 w[8];
    #pragma unroll
    for (int m = 0; m < 8; ++m)
      w[m] = cvt_pk_bf16(s[kb][2 * m] * inv, s[kb][2 * m + 1] * inv);
    u32 t0 = __shfl_xor(w[0], 32), t1 = __shfl_xor(w[1], 32);
    u32 t2 = __shfl_xor(w[2], 32), t3 = __shfl_xor(w[3], 32);
    u32 u0 = __shfl_xor(w[4], 32), u1 = __shfl_xor(w[5], 32);
    u32 u2 = __shfl_xor(w[6], 32), u3 = __shfl_xor(w[7], 32);
    int4 fe = make_int4((int)(hi ? t2 : w[0]), (int)(hi ? t3 : w[1]),
                        (int)(hi ? w[2] : t0), (int)(hi ? w[3] : t1));
    int4 fo = make_int4((int)(hi ? u2 : w[4]), (int)(hi ? u3 : w[5]),
                        (int)(hi ? w[6] : u0), (int)(hi ? w[7] : u1));
    bf16x8 pe = *(bf16x8*)&fe;
    bf16x8 po = *(bf16x8*)&fo;
    #pragma unroll
    for (int dv = 0; dv < 2; ++dv) {
      int row = dv * 32 + l5;
      bf16x8 ve = *(const bf16x8*)((char*)vt_lds + row * 512 +
                                   ((((4 * kb + 0) + hi) ^ (row & 7)) << 4));
      o[dv] = __builtin_amdgcn_mfma_f32_32x32x16_bf16(pe, ve, o[dv], 0, 0, 0);
      bf16x8 vo = *(const bf16x8*)((char*)vt_lds + row * 512 +
                                   ((((4 * kb + 2) + hi) ^ (row & 7)) << 4));
      o[dv] = __builtin_amdgcn_mfma_f32_32x32x16_bf16(po, vo, o[dv], 0, 0, 0);
    }
  }

  int q_base = wave * 32;
  #pragma unroll
  for (int dv = 0; dv < 2; ++dv)
    #pragma unroll
    for (int reg = 0; reg < 16; ++reg) {
      int q = q_base + (reg & 3) + 8 * (reg >> 2) + 4 * hi;
      if (q < NTOK_)
        ows[((long)(bt * NTOK_ + q)) * DIM_ + h * HD_ + dv * 32 + l5] =
            (bf16)o[dv][reg];
    }
}

// ------------------------------------------------------------------- launch
extern "C" void kernel_launch(void* const* d_in, const int* in_sizes, int n_in,
                              void* d_out, int out_size, void* d_ws, size_t ws_size,
                              hipStream_t stream) {
  const float* s_x  = (const float*)d_in[0];
  const float* t_x  = (const float*)d_in[1];
  const float* cpos = (const float*)d_in[2];
  const float* vpos = (const float*)d_in[3];
  const float* q_w  = (const float*)d_in[4];
  const float* q_b  = (const float*)d_in[5];
  const float* kv_w = (const float*)d_in[6];
  const float* kv_b = (const float*)d_in[7];
  const float* p_w  = (const float*)d_in[8];
  const float* p_b  = (const float*)d_in[9];

  char* ws = (char*)d_ws;
  const long SZ_TS = 38535168L;                 // 25088*768*2
  bf16* t_bf  = (bf16*)(ws);                    // t (bf16); later o
  bf16* s_bf  = (bf16*)(ws + SZ_TS);            // s (bf16)
  bf16* wq    = (bf16*)(ws + 2 * SZ_TS);
  bf16* wkv   = (bf16*)(ws + 2 * SZ_TS + 1179648L);
  bf16* wpj   = (bf16*)(ws + 2 * SZ_TS + 3538944L);
  bf16* q_ws  = (bf16*)(ws + 2 * SZ_TS + 4718592L);                  // 38.5MB
  bf16* k_ws  = (bf16*)(ws + 2 * SZ_TS + 4718592L + SZ_TS);          // 44MB
  bf16* vt_ws = (bf16*)(ws + 2 * SZ_TS + 4718592L + SZ_TS + 44040192L); // 44MB
  // total: 208,404,480 bytes

  cast3_kernel<<<1152, 256, 0, stream>>>(q_w, kv_w, p_w, wq, wkv, wpj);
  prep2_kernel<<<18816, 256, 0, stream>>>(t_x, s_x, vpos, cpos, t_bf, s_bf);
  gemm_bt<0, 6><<<196 * 6, 256, 0, stream>>>(t_bf, wq, q_b, q_ws, nullptr, nullptr);
  gemm_bt<1, 12><<<196 * 12, 256, 0, stream>>>(s_bf, wkv, kv_b, k_ws, vt_ws, nullptr);
  attn_kernel<<<1536, 448, 0, stream>>>(q_ws, k_ws, vt_ws, t_bf);
  gemm_bt<2, 6><<<196 * 6, 256, 0, stream>>>(t_bf, wpj, p_b, nullptr, nullptr, (float*)d_out);
}

// Round 4
// 436.382 us; speedup vs baseline: 1.3048x; 1.0407x over previous
//
#include <hip/hip_runtime.h>

typedef __bf16 bf16;
typedef __bf16 bf16x8 __attribute__((ext_vector_type(8)));
typedef __bf16 bf16x4 __attribute__((ext_vector_type(4)));
typedef float  f32x4  __attribute__((ext_vector_type(4)));
typedef float  f32x16 __attribute__((ext_vector_type(16)));
typedef unsigned int u32;

#define H_    12
#define DIM_  768
#define HD_   64
#define NTOK_ 196
#define SCALE_ 0.125f

#define GLOAD_LDS16(g, l)                                                      \
  __builtin_amdgcn_global_load_lds(                                            \
      (const __attribute__((address_space(1))) void*)(g),                      \
      (__attribute__((address_space(3))) void*)(l), 16, 0, 0)

#define VMCNT6 { asm volatile("s_waitcnt vmcnt(6)" ::: "memory");              \
                 __builtin_amdgcn_sched_barrier(0); }
#define VMCNT0 { asm volatile("s_waitcnt vmcnt(0)" ::: "memory");              \
                 __builtin_amdgcn_sched_barrier(0); }

__device__ inline u32 cvt_pk_bf16(float a, float b) {
  u32 r;
  asm volatile("v_cvt_pk_bf16_f32 %0, %1, %2" : "=v"(r) : "v"(a), "v"(b));
  return r;
}

// ------------------------------------------------- fused weight casts (3-in-1)
__global__ __launch_bounds__(256) void cast3_kernel(
    const float* __restrict__ q_w, const float* __restrict__ kv_w,
    const float* __restrict__ p_w, bf16* __restrict__ wq,
    bf16* __restrict__ wkv, bf16* __restrict__ wpj) {
  int b = blockIdx.x;
  const float* src; bf16* dst; int base;
  if (b < 288)      { src = q_w;  dst = wq;  base = b; }
  else if (b < 864) { src = kv_w; dst = wkv; base = b - 288; }
  else              { src = p_w;  dst = wpj; base = b - 864; }
  int e0 = (base * 256 + threadIdx.x) * 8;
  const float4* s4 = (const float4*)(src + e0);
  float4 a0 = s4[0], a1 = s4[1];
  bf16x8 o;
  o[0]=(bf16)a0.x; o[1]=(bf16)a0.y; o[2]=(bf16)a0.z; o[3]=(bf16)a0.w;
  o[4]=(bf16)a1.x; o[5]=(bf16)a1.y; o[6]=(bf16)a1.z; o[7]=(bf16)a1.w;
  *(bf16x8*)(dst + e0) = o;
}

// --------------------------------- fused pos-embed add + bf16 cast (both streams)
__global__ __launch_bounds__(256) void prep2_kernel(
    const float* __restrict__ t_x, const float* __restrict__ s_x,
    const float* __restrict__ vpos, const float* __restrict__ cpos,
    bf16* __restrict__ t_bf, bf16* __restrict__ s_bf) {
  int b = blockIdx.x;
  const float* src; const float* pos; bf16* dst; int mode;
  if (b < 9408) { src = t_x; pos = vpos; dst = t_bf; mode = 0; }
  else          { src = s_x; pos = cpos; dst = s_bf; mode = 1; b -= 9408; }
  int idx = b * 256 + threadIdx.x;
  int e0 = idx * 8;
  int m = e0 / DIM_;
  int c = e0 - m * DIM_;
  int n = m % NTOK_;
  long srow = (mode == 0) ? (long)m : ((long)(m / NTOK_) * 197 + 1 + n);
  const float4* s4 = (const float4*)(src + srow * DIM_ + c);
  const float4* p4 = (const float4*)(pos + (long)n * DIM_ + c);
  float4 a0 = s4[0], a1 = s4[1];
  float4 b0 = p4[0], b1 = p4[1];
  bf16x8 o;
  o[0]=(bf16)(a0.x+b0.x); o[1]=(bf16)(a0.y+b0.y);
  o[2]=(bf16)(a0.z+b0.z); o[3]=(bf16)(a0.w+b0.w);
  o[4]=(bf16)(a1.x+b1.x); o[5]=(bf16)(a1.y+b1.y);
  o[6]=(bf16)(a1.z+b1.z); o[7]=(bf16)(a1.w+b1.w);
  *(bf16x8*)(dst + (long)m * DIM_ + c) = o;
}

// ---------------------------------------------------- pipelined GEMM (BT B)
// 256x128 tile, BK=64, 8 waves (4m x 2n, 64x64 per wave), 32x32x16 MFMA,
// 2x48KB LDS dbuf, counted vmcnt(6) across raw barriers (T3/T4), T2 swizzle
// via pre-swizzled global src + XOR'd ds_read, T5 setprio, T1 bijective XCD
// swizzle. MODE 0: q(*SCALE)->q_ws[pair][196][64]; MODE 1: k->k_ws[pair][224]
// [64], v->vt_ws[pair][64][224]; MODE 2: proj fp32 -> d_out.
template<int MODE, int NBN>
__global__ __launch_bounds__(512, 2) void gemm8(
    const bf16* __restrict__ A, const bf16* __restrict__ Bt,
    const float* __restrict__ bias,
    bf16* __restrict__ out0, bf16* __restrict__ out1, float* __restrict__ outf) {
  __shared__ __align__(16) bf16 lds[2][24576];   // 48 KB per buf: A 32K + B 16K
  constexpr int NWG = 98 * NBN;
  constexpr int q8 = NWG / 8, r8 = NWG % 8;

  int bid = blockIdx.x;
  int xcd = bid & 7, ii = bid >> 3;
  int wgid = (xcd < r8 ? xcd * (q8 + 1) : r8 * (q8 + 1) + (xcd - r8) * q8) + ii;
  int bm = wgid / NBN, bn = wgid - bm * NBN;

  int tid = threadIdx.x;
  int wave = tid >> 6, lane = tid & 63;
  int hi = lane >> 5, l5 = lane & 31;
  int wm = wave >> 1, wn = wave & 1;

  const char* Ac = (const char*)(A + (long)bm * 256 * 768);
  const char* Bc = (const char*)(Bt + (long)bn * 128 * 768);

  int rbase = wave * 8 + (lane >> 3);            // staged row (per tt: +64)
  int sl16 = ((lane & 7) ^ (lane >> 3)) << 4;    // pre-swizzled src slot

  auto stage = [&](int buf, int kt) {
    long kb = (long)kt * 128;
    char* lb = (char*)&lds[buf][0];
    #pragma unroll
    for (int tt = 0; tt < 4; ++tt) {
      long row = rbase + tt * 64;
      GLOAD_LDS16(Ac + row * 1536 + kb + sl16, lb + (wave + 8 * tt) * 1024);
    }
    #pragma unroll
    for (int tt = 0; tt < 2; ++tt) {
      long row = rbase + tt * 64;
      GLOAD_LDS16(Bc + row * 1536 + kb + sl16, lb + 32768 + (wave + 8 * tt) * 1024);
    }
  };

  f32x16 acc[2][2] = {};

  int sw[4];
  #pragma unroll
  for (int kf = 0; kf < 4; ++kf) sw[kf] = (((kf * 2 + hi) ^ (l5 & 7)) << 4);

  stage(0, 0);
  stage(1, 1);
  VMCNT6;                                        // buf0's 6 loads landed
  __builtin_amdgcn_s_barrier();

  int cur = 0;
  for (int kt = 0; kt < 12; ++kt) {
    const char* Al = (const char*)&lds[cur][0];
    const char* Bl = Al + 32768;
    bf16x8 a[2][4], b[2][4];
    #pragma unroll
    for (int mi = 0; mi < 2; ++mi) {
      int rb = (wm * 64 + mi * 32 + l5) * 128;
      #pragma unroll
      for (int kf = 0; kf < 4; ++kf)
        a[mi][kf] = *(const bf16x8*)(Al + rb + sw[kf]);
    }
    #pragma unroll
    for (int ni = 0; ni < 2; ++ni) {
      int rb = (wn * 64 + ni * 32 + l5) * 128;
      #pragma unroll
      for (int kf = 0; kf < 4; ++kf)
        b[ni][kf] = *(const bf16x8*)(Bl + rb + sw[kf]);
    }
    __builtin_amdgcn_s_setprio(1);
    #pragma unroll
    for (int kf = 0; kf < 4; ++kf)
      #pragma unroll
      for (int mi = 0; mi < 2; ++mi)
        #pragma unroll
        for (int ni = 0; ni < 2; ++ni)
          acc[mi][ni] = __builtin_amdgcn_mfma_f32_32x32x16_bf16(
              a[mi][kf], b[ni][kf], acc[mi][ni], 0, 0, 0);
    __builtin_amdgcn_s_setprio(0);

    __builtin_amdgcn_s_barrier();                // all waves done reading cur
    if (kt < 10) {
      stage(cur, kt + 2);                        // overwrite cur with kt+2
      VMCNT6;                                    // kt+1's 6 loads landed
    } else {
      VMCNT0;                                    // tail drain
    }
    __builtin_amdgcn_s_barrier();                // kt+1 visible to all waves
    cur ^= 1;
  }

  // epilogue: C row = bm*256 + wm*64 + mi*32 + rq*8 + hi*4 + jj; col = bn*128
  // + wn*64 + ni*32 + l5  (32x32 C-layout, attn-verified)
  float bv[2];
  int colv[2];
  #pragma unroll
  for (int ni = 0; ni < 2; ++ni) {
    colv[ni] = bn * 128 + wn * 64 + ni * 32 + l5;
    bv[ni] = bias[colv[ni]];
  }
  #pragma unroll
  for (int mi = 0; mi < 2; ++mi) {
    #pragma unroll
    for (int rq = 0; rq < 4; ++rq) {
      int row0 = bm * 256 + wm * 64 + mi * 32 + rq * 8 + hi * 4;
      int bt = row0 / NTOK_;
      int tok0 = row0 - bt * NTOK_;               // multiple of 4
      #pragma unroll
      for (int ni = 0; ni < 2; ++ni) {
        int col = colv[ni];
        if (MODE == 0) {
          int hh = col >> 6, dd = col & 63;
          #pragma unroll
          for (int jj = 0; jj < 4; ++jj)
            out0[(((long)bt * H_ + hh) * NTOK_ + tok0 + jj) * HD_ + dd] =
                (bf16)((acc[mi][ni][rq * 4 + jj] + bv[ni]) * SCALE_);
        } else if (MODE == 1) {
          if (col < DIM_) {
            int hh = col >> 6, dd = col & 63;
            #pragma unroll
            for (int jj = 0; jj < 4; ++jj)
              out0[(((long)bt * H_ + hh) * 224 + tok0 + jj) * HD_ + dd] =
                  (bf16)(acc[mi][ni][rq * 4 + jj] + bv[ni]);
          } else {
            int hh = (col - DIM_) >> 6, dd = col & 63;
            bf16x4 pk;
            #pragma unroll
            for (int jj = 0; jj < 4; ++jj)
              pk[jj] = (bf16)(acc[mi][ni][rq * 4 + jj] + bv[ni]);
            *(bf16x4*)(out1 + (((long)bt * H_ + hh) * HD_ + dd) * 224 + tok0) = pk;
          }
        } else {
          #pragma unroll
          for (int jj = 0; jj < 4; ++jj)
            outf[(long)(row0 + jj) * DIM_ + col] = acc[mi][ni][rq * 4 + jj] + bv[ni];
        }
      }
    }
  }
}

// ----------------------------------------------------------------- attention
// 1 block = 1 (bt,h) pair; 7 waves; 32x32x16 MFMA; in-register softmax.
__global__ __launch_bounds__(448) void attn_kernel(
    const bf16* __restrict__ qws, const bf16* __restrict__ kws,
    const bf16* __restrict__ vtws, bf16* __restrict__ ows) {
  __shared__ __align__(16) bf16 k_lds[224 * 64];    // rows 128B = 8 slots
  __shared__ __align__(16) bf16 vt_lds[64 * 256];   // rows 512B = 32 slots
  int pair = blockIdx.x;
  int bt = pair / H_, h = pair - bt * H_;
  int tid = threadIdx.x;
  int wave = tid >> 6, lane = tid & 63;
  int hi = lane >> 5, l5 = lane & 31;

  const char* Kg = (const char*)(kws + (long)pair * 224 * 64);   // stride 128B
  const char* Vg = (const char*)(vtws + (long)pair * 64 * 224);  // stride 448B

  for (int ch = wave; ch < 60; ch += 7) {
    if (ch < 28) {
      int i = ch * 64 + lane;
      int r = i >> 3, p = i & 7;
      GLOAD_LDS16(Kg + (long)r * 128 + ((p ^ (r & 7)) * 16),
                  (char*)k_lds + ch * 1024);
    } else {
      int i = (ch - 28) * 64 + lane;
      int r = i >> 5, p = i & 31;
      int gs = p ^ (r & 7);
      if (gs > 27) gs = 27;   // junk slot, never read; keep in-bounds
      GLOAD_LDS16(Vg + (long)r * 448 + gs * 16,
                  (char*)vt_lds + (ch - 28) * 1024);
    }
  }

  int qr = wave * 32 + l5;
  if (qr > 195) qr = 195;                     // clamp; results masked at store
  const bf16* Qp = qws + (long)pair * NTOK_ * HD_ + qr * 64 + hi * 8;
  bf16x8 qf[4];
  #pragma unroll
  for (int c = 0; c < 4; ++c) qf[c] = *(const bf16x8*)(Qp + c * 16);

  __syncthreads();

  f32x16 s[7] = {};
  #pragma unroll
  for (int kb = 0; kb < 7; ++kb) {
    #pragma unroll
    for (int c = 0; c < 4; ++c) {
      int row = kb * 32 + l5;
      bf16x8 kf = *(const bf16x8*)((char*)k_lds + row * 128 +
                                   (((c * 2 + hi) ^ (row & 7)) << 4));
      s[kb] = __builtin_amdgcn_mfma_f32_32x32x16_bf16(kf, qf[c], s[kb], 0, 0, 0);
    }
  }

  float mx = -1e30f;
  #pragma unroll
  for (int kb = 0; kb < 7; ++kb)
    #pragma unroll
    for (int reg = 0; reg < 16; ++reg) {
      int kk = kb * 32 + (reg & 3) + 8 * (reg >> 2) + 4 * hi;
      float v = s[kb][reg];
      if (kk >= NTOK_) v = -1e30f;
      s[kb][reg] = v;
      mx = fmaxf(mx, v);
    }
  mx = fmaxf(mx, __shfl_xor(mx, 32));
  float sum = 0.f;
  #pragma unroll
  for (int kb = 0; kb < 7; ++kb)
    #pragma unroll
    for (int reg = 0; reg < 16; ++reg) {
      float e = __expf(s[kb][reg] - mx);
      s[kb][reg] = e;
      sum += e;
    }
  sum += __shfl_xor(sum, 32);
  float inv = 1.f / sum;

  f32x16 o[2] = {};
  #pragma unroll
  for (int kb = 0; kb < 7; ++kb) {
    u32 w[8];
    #pragma unroll
    for (int m = 0; m < 8; ++m)
      w[m] = cvt_pk_bf16(s[kb][2 * m] * inv, s[kb][2 * m + 1] * inv);
    u32 t0 = __shfl_xor(w[0], 32), t1 = __shfl_xor(w[1], 32);
    u32 t2 = __shfl_xor(w[2], 32), t3 = __shfl_xor(w[3], 32);
    u32 u0 = __shfl_xor(w[4], 32), u1 = __shfl_xor(w[5], 32);
    u32 u2 = __shfl_xor(w[6], 32), u3 = __shfl_xor(w[7], 32);
    int4 fe = make_int4((int)(hi ? t2 : w[0]), (int)(hi ? t3 : w[1]),
                        (int)(hi ? w[2] : t0), (int)(hi ? w[3] : t1));
    int4 fo = make_int4((int)(hi ? u2 : w[4]), (int)(hi ? u3 : w[5]),
                        (int)(hi ? w[6] : u0), (int)(hi ? w[7] : u1));
    bf16x8 pe = *(bf16x8*)&fe;
    bf16x8 po = *(bf16x8*)&fo;
    #pragma unroll
    for (int dv = 0; dv < 2; ++dv) {
      int row = dv * 32 + l5;
      bf16x8 ve = *(const bf16x8*)((char*)vt_lds + row * 512 +
                                   ((((4 * kb + 0) + hi) ^ (row & 7)) << 4));
      o[dv] = __builtin_amdgcn_mfma_f32_32x32x16_bf16(pe, ve, o[dv], 0, 0, 0);
      bf16x8 vo = *(const bf16x8*)((char*)vt_lds + row * 512 +
                                   ((((4 * kb + 2) + hi) ^ (row & 7)) << 4));
      o[dv] = __builtin_amdgcn_mfma_f32_32x32x16_bf16(po, vo, o[dv], 0, 0, 0);
    }
  }

  int q_base = wave * 32;
  #pragma unroll
  for (int dv = 0; dv < 2; ++dv)
    #pragma unroll
    for (int reg = 0; reg < 16; ++reg) {
      int q = q_base + (reg & 3) + 8 * (reg >> 2) + 4 * hi;
      if (q < NTOK_)
        ows[((long)(bt * NTOK_ + q)) * DIM_ + h * HD_ + dv * 32 + l5] =
            (bf16)o[dv][reg];
    }
}

// ------------------------------------------------------------------- launch
extern "C" void kernel_launch(void* const* d_in, const int* in_sizes, int n_in,
                              void* d_out, int out_size, void* d_ws, size_t ws_size,
                              hipStream_t stream) {
  const float* s_x  = (const float*)d_in[0];
  const float* t_x  = (const float*)d_in[1];
  const float* cpos = (const float*)d_in[2];
  const float* vpos = (const float*)d_in[3];
  const float* q_w  = (const float*)d_in[4];
  const float* q_b  = (const float*)d_in[5];
  const float* kv_w = (const float*)d_in[6];
  const float* kv_b = (const float*)d_in[7];
  const float* p_w  = (const float*)d_in[8];
  const float* p_b  = (const float*)d_in[9];

  char* ws = (char*)d_ws;
  const long SZ_TS = 38535168L;                 // 25088*768*2
  bf16* t_bf  = (bf16*)(ws);                    // t (bf16); later o
  bf16* s_bf  = (bf16*)(ws + SZ_TS);            // s (bf16)
  bf16* wq    = (bf16*)(ws + 2 * SZ_TS);
  bf16* wkv   = (bf16*)(ws + 2 * SZ_TS + 1179648L);
  bf16* wpj   = (bf16*)(ws + 2 * SZ_TS + 3538944L);
  bf16* q_ws  = (bf16*)(ws + 2 * SZ_TS + 4718592L);                  // 38.5MB
  bf16* k_ws  = (bf16*)(ws + 2 * SZ_TS + 4718592L + SZ_TS);          // 44MB
  bf16* vt_ws = (bf16*)(ws + 2 * SZ_TS + 4718592L + SZ_TS + 44040192L); // 44MB
  // total: 208,404,480 bytes

  cast3_kernel<<<1152, 256, 0, stream>>>(q_w, kv_w, p_w, wq, wkv, wpj);
  prep2_kernel<<<18816, 256, 0, stream>>>(t_x, s_x, vpos, cpos, t_bf, s_bf);
  gemm8<0, 6><<<588, 512, 0, stream>>>(t_bf, wq, q_b, q_ws, nullptr, nullptr);
  gemm8<1, 12><<<1176, 512, 0, stream>>>(s_bf, wkv, kv_b, k_ws, vt_ws, nullptr);
  attn_kernel<<<1536, 448, 0, stream>>>(q_ws, k_ws, vt_ws, t_bf);
  gemm8<2, 6><<<588, 512, 0, stream>>>(t_bf, wpj, p_b, nullptr, nullptr, (float*)d_out);
}

// Round 6
// 425.683 us; speedup vs baseline: 1.3376x; 1.0251x over previous
//
#include <hip/hip_runtime.h>

typedef __bf16 bf16;
typedef __bf16 bf16x8 __attribute__((ext_vector_type(8)));
typedef __bf16 bf16x4 __attribute__((ext_vector_type(4)));
typedef float  f32x4  __attribute__((ext_vector_type(4)));
typedef float  f32x16 __attribute__((ext_vector_type(16)));
typedef unsigned int u32;

#define H_    12
#define DIM_  768
#define HD_   64
#define NTOK_ 196
#define SCALE_ 0.125f

#define GLOAD_LDS16(g, l)                                                      \
  __builtin_amdgcn_global_load_lds(                                            \
      (const __attribute__((address_space(1))) void*)(g),                      \
      (__attribute__((address_space(3))) void*)(l), 16, 0, 0)

__device__ inline u32 cvt_pk_bf16(float a, float b) {
  u32 r;
  asm volatile("v_cvt_pk_bf16_f32 %0, %1, %2" : "=v"(r) : "v"(a), "v"(b));
  return r;
}

// ------------------------------------------------- fused weight casts (3-in-1)
__global__ __launch_bounds__(256) void cast3_kernel(
    const float* __restrict__ q_w, const float* __restrict__ kv_w,
    const float* __restrict__ p_w, bf16* __restrict__ wq,
    bf16* __restrict__ wkv, bf16* __restrict__ wpj) {
  int b = blockIdx.x;
  const float* src; bf16* dst; int base;
  if (b < 288)      { src = q_w;  dst = wq;  base = b; }
  else if (b < 864) { src = kv_w; dst = wkv; base = b - 288; }
  else              { src = p_w;  dst = wpj; base = b - 864; }
  int e0 = (base * 256 + threadIdx.x) * 8;
  const float4* s4 = (const float4*)(src + e0);
  float4 a0 = s4[0], a1 = s4[1];
  bf16x8 o;
  o[0]=(bf16)a0.x; o[1]=(bf16)a0.y; o[2]=(bf16)a0.z; o[3]=(bf16)a0.w;
  o[4]=(bf16)a1.x; o[5]=(bf16)a1.y; o[6]=(bf16)a1.z; o[7]=(bf16)a1.w;
  *(bf16x8*)(dst + e0) = o;
}

// --------------------------------- fused pos-embed add + bf16 cast (both streams)
__global__ __launch_bounds__(256) void prep2_kernel(
    const float* __restrict__ t_x, const float* __restrict__ s_x,
    const float* __restrict__ vpos, const float* __restrict__ cpos,
    bf16* __restrict__ t_bf, bf16* __restrict__ s_bf) {
  int b = blockIdx.x;
  const float* src; const float* pos; bf16* dst; int mode;
  if (b < 9408) { src = t_x; pos = vpos; dst = t_bf; mode = 0; }
  else          { src = s_x; pos = cpos; dst = s_bf; mode = 1; b -= 9408; }
  int idx = b * 256 + threadIdx.x;
  int e0 = idx * 8;
  int m = e0 / DIM_;
  int c = e0 - m * DIM_;
  int n = m % NTOK_;
  long srow = (mode == 0) ? (long)m : ((long)(m / NTOK_) * 197 + 1 + n);
  const float4* s4 = (const float4*)(src + srow * DIM_ + c);
  const float4* p4 = (const float4*)(pos + (long)n * DIM_ + c);
  float4 a0 = s4[0], a1 = s4[1];
  float4 b0 = p4[0], b1 = p4[1];
  bf16x8 o;
  o[0]=(bf16)(a0.x+b0.x); o[1]=(bf16)(a0.y+b0.y);
  o[2]=(bf16)(a0.z+b0.z); o[3]=(bf16)(a0.w+b0.w);
  o[4]=(bf16)(a1.x+b1.x); o[5]=(bf16)(a1.y+b1.y);
  o[6]=(bf16)(a1.z+b1.z); o[7]=(bf16)(a1.w+b1.w);
  *(bf16x8*)(dst + (long)m * DIM_ + c) = o;
}

// ---------------------------------------------------- pipelined GEMM (BT B)
// 128 x TN tile (TN=256 kv, 128 q/proj), BK=32, 4 waves (2m x 2n), 16x16x32
// MFMA, r3's PROVEN conflict-free LDS geometry (64B rows, slot^(r>>1)&3),
// counted-vmcnt dbuf schedule, 2 blocks/CU (LDS padded to 56KB), T1 + T5.
// MODE 0: q (*SCALE) -> q_ws[pair][196][64]
// MODE 1: kv -> k_ws[pair][224][64], v -> vt_ws[pair][64][224]
// MODE 2: proj -> d_out fp32
template<int MODE>
__global__ __launch_bounds__(256, 2) void gemmP(
    const bf16* __restrict__ A, const bf16* __restrict__ Bt,
    const float* __restrict__ bias,
    bf16* __restrict__ out0, bf16* __restrict__ out1, float* __restrict__ outf) {
  constexpr int TN  = (MODE == 1) ? 256 : 128;
  constexpr int NI  = TN / 32;          // b-frags per wave: 8 or 4
  constexpr int NBP = TN / 64;          // B stage passes: 4 or 2
  // 56KB total -> exactly 2 blocks/CU
  __shared__ __align__(16) char smem[2][28672];

  // T1 bijective chunked swizzle, NWG = 1176 (q8=147, r8=0)
  int bid = blockIdx.x;
  int wgid = (bid & 7) * 147 + (bid >> 3);
  int bm = wgid / 6, bn = wgid - bm * 6;

  int tid = threadIdx.x;
  int wave = tid >> 6, lane = tid & 63;
  int li = lane & 15, g = lane >> 4;
  int wm = wave >> 1, wn = wave & 1;

  const char* Ac = (const char*)(A + (long)bm * 128 * 768);
  const char* Bc = (const char*)(Bt + (long)bn * TN * 768);

  // stage: 64B rows, 4 slots; LDS[r][p'] = G[r][p' ^ ((r>>1)&3)]
  int srow = wave * 16 + (lane >> 2);                  // + pass*64
  long sl = ((lane & 3) ^ ((lane >> 3) & 3)) << 4;     // src slot bytes
  auto stage = [&](int buf, int kt) {
    long kb = (long)kt * 64;
    char* lb = (char*)smem[buf];
    #pragma unroll
    for (int p = 0; p < 2; ++p) {                      // A: 128 rows = 8KB
      long r = srow + p * 64;
      GLOAD_LDS16(Ac + r * 1536 + kb + sl, lb + p * 4096 + wave * 1024);
    }
    #pragma unroll
    for (int p = 0; p < NBP; ++p) {                    // B: TN rows
      long r = srow + p * 64;
      GLOAD_LDS16(Bc + r * 1536 + kb + sl, lb + 8192 + p * 4096 + wave * 1024);
    }
  };

  f32x4 acc[4][NI] = {};
  int swb = ((g ^ ((li >> 1) & 3)) << 4);              // read swizzle (const!)

  stage(0, 0);
  stage(1, 1);
  if constexpr (MODE == 1) {
    asm volatile("s_waitcnt vmcnt(6)" ::: "memory");
  } else {
    asm volatile("s_waitcnt vmcnt(4)" ::: "memory");
  }
  __builtin_amdgcn_sched_barrier(0);
  __builtin_amdgcn_s_barrier();

  int cur = 0;
  for (int kt = 0; kt < 24; ++kt) {
    const char* Al = (const char*)smem[cur];
    const char* Bl = Al + 8192;
    bf16x8 a[4], b[NI];
    #pragma unroll
    for (int mi = 0; mi < 4; ++mi) {
      int ra = wm * 64 + mi * 16 + li;
      a[mi] = *(const bf16x8*)(Al + ra * 64 + swb);
    }
    #pragma unroll
    for (int ni = 0; ni < NI; ++ni) {
      int rb = wn * (TN / 2) + ni * 16 + li;
      b[ni] = *(const bf16x8*)(Bl + rb * 64 + swb);
    }
    __builtin_amdgcn_s_setprio(1);
    #pragma unroll
    for (int mi = 0; mi < 4; ++mi)
      #pragma unroll
      for (int ni = 0; ni < NI; ++ni)
        acc[mi][ni] = __builtin_amdgcn_mfma_f32_16x16x32_bf16(
            a[mi], b[ni], acc[mi][ni], 0, 0, 0);
    __builtin_amdgcn_s_setprio(0);

    __builtin_amdgcn_s_barrier();                 // all waves done reading cur
    if (kt < 22) {
      stage(cur, kt + 2);                         // overwrite cur with kt+2
      if constexpr (MODE == 1) {
        asm volatile("s_waitcnt vmcnt(6)" ::: "memory");
      } else {
        asm volatile("s_waitcnt vmcnt(4)" ::: "memory");
      }
    } else {
      asm volatile("s_waitcnt vmcnt(0)" ::: "memory");
    }
    __builtin_amdgcn_sched_barrier(0);
    __builtin_amdgcn_s_barrier();                 // kt+1 visible to all waves
    cur ^= 1;
  }

  // epilogue: C row = bm*128 + wm*64 + mi*16 + g*4 + jj;
  //           col = bn*TN + wn*(TN/2) + ni*16 + li   (16x16 C-layout, m89)
  #pragma unroll
  for (int ni = 0; ni < NI; ++ni) {
    int col = bn * TN + wn * (TN / 2) + ni * 16 + li;
    float bv = bias[col];
    #pragma unroll
    for (int mi = 0; mi < 4; ++mi) {
      int row0 = bm * 128 + wm * 64 + mi * 16 + g * 4;   // multiple of 4
      int bt = row0 / NTOK_;
      int tok0 = row0 - bt * NTOK_;                      // quad never crosses bt
      if (MODE == 0) {
        int hh = col >> 6, dd = col & 63;
        #pragma unroll
        for (int jj = 0; jj < 4; ++jj)
          out0[(((long)bt * H_ + hh) * NTOK_ + tok0 + jj) * HD_ + dd] =
              (bf16)((acc[mi][ni][jj] + bv) * SCALE_);
      } else if (MODE == 1) {
        if (col < DIM_) {
          int hh = col >> 6, dd = col & 63;
          #pragma unroll
          for (int jj = 0; jj < 4; ++jj)
            out0[(((long)bt * H_ + hh) * 224 + tok0 + jj) * HD_ + dd] =
                (bf16)(acc[mi][ni][jj] + bv);
        } else {
          int c2 = col - DIM_;
          int hh = c2 >> 6, dd = c2 & 63;
          bf16x4 pk;
          #pragma unroll
          for (int jj = 0; jj < 4; ++jj) pk[jj] = (bf16)(acc[mi][ni][jj] + bv);
          *(bf16x4*)(out1 + (((long)bt * H_ + hh) * HD_ + dd) * 224 + tok0) = pk;
        }
      } else {
        #pragma unroll
        for (int jj = 0; jj < 4; ++jj)
          outf[(long)(row0 + jj) * DIM_ + col] = acc[mi][ni][jj] + bv;
      }
    }
  }
}

// ----------------------------------------------------------------- attention
// 1 block = 1 (bt,h) pair; 7 waves; 32x32x16 MFMA; in-register softmax.
__global__ __launch_bounds__(448) void attn_kernel(
    const bf16* __restrict__ qws, const bf16* __restrict__ kws,
    const bf16* __restrict__ vtws, bf16* __restrict__ ows) {
  __shared__ __align__(16) bf16 k_lds[224 * 64];    // rows 128B = 8 slots
  __shared__ __align__(16) bf16 vt_lds[64 * 256];   // rows 512B = 32 slots
  int pair = blockIdx.x;
  int bt = pair / H_, h = pair - bt * H_;
  int tid = threadIdx.x;
  int wave = tid >> 6, lane = tid & 63;
  int hi = lane >> 5, l5 = lane & 31;

  const char* Kg = (const char*)(kws + (long)pair * 224 * 64);   // stride 128B
  const char* Vg = (const char*)(vtws + (long)pair * 64 * 224);  // stride 448B

  for (int ch = wave; ch < 60; ch += 7) {
    if (ch < 28) {
      int i = ch * 64 + lane;
      int r = i >> 3, p = i & 7;
      GLOAD_LDS16(Kg + (long)r * 128 + ((p ^ (r & 7)) * 16),
                  (char*)k_lds + ch * 1024);
    } else {
      int i = (ch - 28) * 64 + lane;
      int r = i >> 5, p = i & 31;
      int gs = p ^ (r & 7);
      if (gs > 27) gs = 27;   // junk slot, never read; keep in-bounds
      GLOAD_LDS16(Vg + (long)r * 448 + gs * 16,
                  (char*)vt_lds + (ch - 28) * 1024);
    }
  }

  int qr = wave * 32 + l5;
  if (qr > 195) qr = 195;                     // clamp; results masked at store
  const bf16* Qp = qws + (long)pair * NTOK_ * HD_ + qr * 64 + hi * 8;
  bf16x8 qf[4];
  #pragma unroll
  for (int c = 0; c < 4; ++c) qf[c] = *(const bf16x8*)(Qp + c * 16);

  __syncthreads();

  f32x16 s[7] = {};
  #pragma unroll
  for (int kb = 0; kb < 7; ++kb) {
    #pragma unroll
    for (int c = 0; c < 4; ++c) {
      int row = kb * 32 + l5;
      bf16x8 kf = *(const bf16x8*)((char*)k_lds + row * 128 +
                                   (((c * 2 + hi) ^ (row & 7)) << 4));
      s[kb] = __builtin_amdgcn_mfma_f32_32x32x16_bf16(kf, qf[c], s[kb], 0, 0, 0);
    }
  }

  float mx = -1e30f;
  #pragma unroll
  for (int kb = 0; kb < 7; ++kb)
    #pragma unroll
    for (int reg = 0; reg < 16; ++reg) {
      int kk = kb * 32 + (reg & 3) + 8 * (reg >> 2) + 4 * hi;
      float v = s[kb][reg];
      if (kk >= NTOK_) v = -1e30f;
      s[kb][reg] = v;
      mx = fmaxf(mx, v);
    }
  mx = fmaxf(mx, __shfl_xor(mx, 32));
  float sum = 0.f;
  #pragma unroll
  for (int kb = 0; kb < 7; ++kb)
    #pragma unroll
    for (int reg = 0; reg < 16; ++reg) {
      float e = __expf(s[kb][reg] - mx);
      s[kb][reg] = e;
      sum += e;
    }
  sum += __shfl_xor(sum, 32);
  float inv = 1.f / sum;

  f32x16 o[2] = {};
  #pragma unroll
  for (int kb = 0; kb < 7; ++kb) {
    u32 w[8];
    #pragma unroll
    for (int m = 0; m < 8; ++m)
      w[m] = cvt_pk_bf16(s[kb][2 * m] * inv, s[kb][2 * m + 1] * inv);
    u32 t0 = __shfl_xor(w[0], 32), t1 = __shfl_xor(w[1], 32);
    u32 t2 = __shfl_xor(w[2], 32), t3 = __shfl_xor(w[3], 32);
    u32 u0 = __shfl_xor(w[4], 32), u1 = __shfl_xor(w[5], 32);
    u32 u2 = __shfl_xor(w[6], 32), u3 = __shfl_xor(w[7], 32);
    int4 fe = make_int4((int)(hi ? t2 : w[0]), (int)(hi ? t3 : w[1]),
                        (int)(hi ? w[2] : t0), (int)(hi ? w[3] : t1));
    int4 fo = make_int4((int)(hi ? u2 : w[4]), (int)(hi ? u3 : w[5]),
                        (int)(hi ? w[6] : u0), (int)(hi ? w[7] : u1));
    bf16x8 pe = *(bf16x8*)&fe;
    bf16x8 po = *(bf16x8*)&fo;
    #pragma unroll
    for (int dv = 0; dv < 2; ++dv) {
      int row = dv * 32 + l5;
      bf16x8 ve = *(const bf16x8*)((char*)vt_lds + row * 512 +
                                   ((((4 * kb + 0) + hi) ^ (row & 7)) << 4));
      o[dv] = __builtin_amdgcn_mfma_f32_32x32x16_bf16(pe, ve, o[dv], 0, 0, 0);
      bf16x8 vo = *(const bf16x8*)((char*)vt_lds + row * 512 +
                                   ((((4 * kb + 2) + hi) ^ (row & 7)) << 4));
      o[dv] = __builtin_amdgcn_mfma_f32_32x32x16_bf16(po, vo, o[dv], 0, 0, 0);
    }
  }

  int q_base = wave * 32;
  #pragma unroll
  for (int dv = 0; dv < 2; ++dv)
    #pragma unroll
    for (int reg = 0; reg < 16; ++reg) {
      int q = q_base + (reg & 3) + 8 * (reg >> 2) + 4 * hi;
      if (q < NTOK_)
        ows[((long)(bt * NTOK_ + q)) * DIM_ + h * HD_ + dv * 32 + l5] =
            (bf16)o[dv][reg];
    }
}

// ------------------------------------------------------------------- launch
extern "C" void kernel_launch(void* const* d_in, const int* in_sizes, int n_in,
                              void* d_out, int out_size, void* d_ws, size_t ws_size,
                              hipStream_t stream) {
  const float* s_x  = (const float*)d_in[0];
  const float* t_x  = (const float*)d_in[1];
  const float* cpos = (const float*)d_in[2];
  const float* vpos = (const float*)d_in[3];
  const float* q_w  = (const float*)d_in[4];
  const float* q_b  = (const float*)d_in[5];
  const float* kv_w = (const float*)d_in[6];
  const float* kv_b = (const float*)d_in[7];
  const float* p_w  = (const float*)d_in[8];
  const float* p_b  = (const float*)d_in[9];

  char* ws = (char*)d_ws;
  const long SZ_TS = 38535168L;                 // 25088*768*2
  bf16* t_bf  = (bf16*)(ws);                    // t (bf16); later o
  bf16* s_bf  = (bf16*)(ws + SZ_TS);            // s (bf16)
  bf16* wq    = (bf16*)(ws + 2 * SZ_TS);
  bf16* wkv   = (bf16*)(ws + 2 * SZ_TS + 1179648L);
  bf16* wpj   = (bf16*)(ws + 2 * SZ_TS + 3538944L);
  bf16* q_ws  = (bf16*)(ws + 2 * SZ_TS + 4718592L);                  // 38.5MB
  bf16* k_ws  = (bf16*)(ws + 2 * SZ_TS + 4718592L + SZ_TS);          // 44MB
  bf16* vt_ws = (bf16*)(ws + 2 * SZ_TS + 4718592L + SZ_TS + 44040192L); // 44MB
  // total: 208,404,480 bytes

  cast3_kernel<<<1152, 256, 0, stream>>>(q_w, kv_w, p_w, wq, wkv, wpj);
  prep2_kernel<<<18816, 256, 0, stream>>>(t_x, s_x, vpos, cpos, t_bf, s_bf);
  gemmP<0><<<1176, 256, 0, stream>>>(t_bf, wq, q_b, q_ws, nullptr, nullptr);
  gemmP<1><<<1176, 256, 0, stream>>>(s_bf, wkv, kv_b, k_ws, vt_ws, nullptr);
  attn_kernel<<<1536, 448, 0, stream>>>(q_ws, k_ws, vt_ws, t_bf);
  gemmP<2><<<1176, 256, 0, stream>>>(t_bf, wpj, p_b, nullptr, nullptr, (float*)d_out);
}